// Round 1
// baseline (2429.005 us; speedup 1.0000x reference)
//
#include <hip/hip_runtime.h>
#include <cstdint>

// Problem constants
#define LYR 2
#define DM  256
#define DFFN 1024
#define NHD 8
#define NPT 4
#define CINC 512
#define BBATCH 8
#define HH2 64
#define WW2 64
#define HWTOT 4096
#define EPSV 1e-5f

constexpr int TS = 64;   // output tile
constexpr int KS = 16;   // k tile
constexpr int PAD = 4;   // LDS pad -> row stride 68 floats (16B aligned)

// ---------------- generic row-major SGEMM: C[M,N] = A[M,K] @ Bw[K,N] + bias, opt relu
__global__ __launch_bounds__(256) void gemm_rm(
    const float* __restrict__ A, const float* __restrict__ Bw,
    const float* __restrict__ bias, float* __restrict__ C,
    int M, int N, int K, int relu)
{
    __shared__ float As[KS][TS + PAD];
    __shared__ float Bs[KS][TS + PAD];
    const int tid = threadIdx.x;
    const int m0 = blockIdx.y * TS;
    const int n0 = blockIdx.x * TS;
    const int tx = tid & 15, ty = tid >> 4;
    float acc[4][4] = {};
    for (int k0 = 0; k0 < K; k0 += KS) {
#pragma unroll
        for (int i = 0; i < 4; ++i) {
            int e = tid + i * 256;
            int k = e & 15, m = e >> 4;
            As[k][m] = A[(size_t)(m0 + m) * K + k0 + k];
        }
#pragma unroll
        for (int i = 0; i < 4; ++i) {
            int e = tid + i * 256;
            int n = e & 63, k = e >> 6;
            int nn = n0 + n;
            Bs[k][n] = (nn < N) ? Bw[(size_t)(k0 + k) * N + nn] : 0.0f;
        }
        __syncthreads();
#pragma unroll
        for (int k = 0; k < KS; ++k) {
            float a[4], bv[4];
#pragma unroll
            for (int i = 0; i < 4; ++i) a[i] = As[k][ty * 4 + i];
#pragma unroll
            for (int j = 0; j < 4; ++j) bv[j] = Bs[k][tx * 4 + j];
#pragma unroll
            for (int i = 0; i < 4; ++i)
#pragma unroll
                for (int j = 0; j < 4; ++j) acc[i][j] += a[i] * bv[j];
        }
        __syncthreads();
    }
#pragma unroll
    for (int i = 0; i < 4; ++i) {
        int m = m0 + ty * 4 + i;
#pragma unroll
        for (int j = 0; j < 4; ++j) {
            int n = n0 + tx * 4 + j;
            if (n < N) {
                float v = acc[i][j] + bias[n];
                if (relu) v = fmaxf(v, 0.0f);
                C[(size_t)m * N + n] = v;
            }
        }
    }
}

// ---------------- proj_in: src[b,p,d] = relu(BN(sum_c x[b,c,p] * W_in[d,c]))
__global__ __launch_bounds__(256) void gemm_projin(
    const float* __restrict__ X, const float* __restrict__ W,
    const float* __restrict__ g, const float* __restrict__ bb,
    const float* __restrict__ mm, const float* __restrict__ vv,
    float* __restrict__ S)
{
    __shared__ float As[KS][TS + PAD];
    __shared__ float Bs[KS][TS + PAD];
    const int tid = threadIdx.x;
    const int b = blockIdx.z;
    const int p0 = blockIdx.y * TS;
    const int d0 = blockIdx.x * TS;
    const int tx = tid & 15, ty = tid >> 4;
    const float* Xb = X + (size_t)b * CINC * HWTOT;
    float acc[4][4] = {};
    for (int c0 = 0; c0 < CINC; c0 += KS) {
#pragma unroll
        for (int i = 0; i < 4; ++i) {          // As[k][m] = X[b, c0+k, p0+m]
            int e = tid + i * 256;
            int m = e & 63, k = e >> 6;
            As[k][m] = Xb[(size_t)(c0 + k) * HWTOT + p0 + m];
        }
#pragma unroll
        for (int i = 0; i < 4; ++i) {          // Bs[k][n] = W[d0+n, c0+k]
            int e = tid + i * 256;
            int k = e & 15, n = e >> 4;
            Bs[k][n] = W[(size_t)(d0 + n) * CINC + c0 + k];
        }
        __syncthreads();
#pragma unroll
        for (int k = 0; k < KS; ++k) {
            float a[4], bv[4];
#pragma unroll
            for (int i = 0; i < 4; ++i) a[i] = As[k][ty * 4 + i];
#pragma unroll
            for (int j = 0; j < 4; ++j) bv[j] = Bs[k][tx * 4 + j];
#pragma unroll
            for (int i = 0; i < 4; ++i)
#pragma unroll
                for (int j = 0; j < 4; ++j) acc[i][j] += a[i] * bv[j];
        }
        __syncthreads();
    }
#pragma unroll
    for (int j = 0; j < 4; ++j) {
        int d = d0 + tx * 4 + j;
        float sc = g[d] * rsqrtf(vv[d] + EPSV);
        float sh = bb[d] - mm[d] * sc;
#pragma unroll
        for (int i = 0; i < 4; ++i) {
            int p = p0 + ty * 4 + i;
            float v = acc[i][j] * sc + sh;
            S[((size_t)b * HWTOT + p) * DM + d] = fmaxf(v, 0.0f);
        }
    }
}

// ---------------- proj_out: out[b,c,p] = relu(BN(sum_d q[b,p,d] * W_out[c,d]))
__global__ __launch_bounds__(256) void gemm_projout(
    const float* __restrict__ Q, const float* __restrict__ W,
    const float* __restrict__ g, const float* __restrict__ bb,
    const float* __restrict__ mm, const float* __restrict__ vv,
    float* __restrict__ Y)
{
    __shared__ float As[KS][TS + PAD];
    __shared__ float Bs[KS][TS + PAD];
    const int tid = threadIdx.x;
    const int b = blockIdx.z;
    const int c0 = blockIdx.y * TS;
    const int p0 = blockIdx.x * TS;
    const int tx = tid & 15, ty = tid >> 4;
    const float* Qb = Q + (size_t)b * HWTOT * DM;
    float acc[4][4] = {};
    for (int k0 = 0; k0 < DM; k0 += KS) {
#pragma unroll
        for (int i = 0; i < 4; ++i) {          // As[k][m] = W[c0+m, k0+k]
            int e = tid + i * 256;
            int k = e & 15, m = e >> 4;
            As[k][m] = W[(size_t)(c0 + m) * DM + k0 + k];
        }
#pragma unroll
        for (int i = 0; i < 4; ++i) {          // Bs[k][n] = Q[b, p0+n, k0+k]
            int e = tid + i * 256;
            int k = e & 15, n = e >> 4;
            Bs[k][n] = Qb[(size_t)(p0 + n) * DM + k0 + k];
        }
        __syncthreads();
#pragma unroll
        for (int k = 0; k < KS; ++k) {
            float a[4], bv[4];
#pragma unroll
            for (int i = 0; i < 4; ++i) a[i] = As[k][ty * 4 + i];
#pragma unroll
            for (int j = 0; j < 4; ++j) bv[j] = Bs[k][tx * 4 + j];
#pragma unroll
            for (int i = 0; i < 4; ++i)
#pragma unroll
                for (int j = 0; j < 4; ++j) acc[i][j] += a[i] * bv[j];
        }
        __syncthreads();
    }
#pragma unroll
    for (int i = 0; i < 4; ++i) {
        int c = c0 + ty * 4 + i;
        float sc = g[c] * rsqrtf(vv[c] + EPSV);
        float sh = bb[c] - mm[c] * sc;
#pragma unroll
        for (int j = 0; j < 4; ++j) {
            int p = p0 + tx * 4 + j;
            float v = acc[i][j] * sc + sh;
            Y[((size_t)b * CINC + c) * HWTOT + p] = fmaxf(v, 0.0f);
        }
    }
}

// ---------------- deformable sampling: one block per (b,q)
__global__ __launch_bounds__(256) void sample_kernel(
    const float* __restrict__ val,     // (B*HW, D)
    const float* __restrict__ off,     // (B*HW, 64)
    const float* __restrict__ attnlog, // (B*HW, 32)
    float* __restrict__ oms)           // (B*HW, D)
{
    const int bq = blockIdx.x;
    const int q = bq & (HWTOT - 1);
    const int b = bq >> 12;
    const int t = threadIdx.x;
    __shared__ float s_off[64];
    __shared__ float s_attn[32];
    __shared__ int   s_idx[32][4];
    __shared__ float s_w[32][4];
    if (t < 64) s_off[t] = off[(size_t)bq * 64 + t];
    else if (t < 96) s_attn[t - 64] = attnlog[(size_t)bq * 32 + (t - 64)];
    __syncthreads();
    if (t < 8) {  // softmax over NP=4 per head
        float mx = -1e30f;
#pragma unroll
        for (int p = 0; p < 4; ++p) mx = fmaxf(mx, s_attn[t * 4 + p]);
        float e[4], s = 0.0f;
#pragma unroll
        for (int p = 0; p < 4; ++p) { e[p] = __expf(s_attn[t * 4 + p] - mx); s += e[p]; }
        float inv = 1.0f / s;
#pragma unroll
        for (int p = 0; p < 4; ++p) s_attn[t * 4 + p] = e[p] * inv;
    }
    if (t >= 32 && t < 64) {  // corner indices + weights for (h,p)
        int hp = t - 32;
        int ix = q & 63, iy = q >> 6;
        float rx = (ix + 0.5f) * (1.0f / 64.0f);
        float ry = (iy + 0.5f) * (1.0f / 64.0f);
        float lx = rx + s_off[hp * 2 + 0] * (1.0f / 64.0f);
        float ly = ry + s_off[hp * 2 + 1] * (1.0f / 64.0f);
        float gx = lx * 64.0f - 0.5f;
        float gy = ly * 64.0f - 0.5f;
        float x0f = floorf(gx), y0f = floorf(gy);
        float wx = gx - x0f, wy = gy - y0f;
        int x0 = (int)x0f, y0 = (int)y0f;
#pragma unroll
        for (int c = 0; c < 4; ++c) {
            int xi = x0 + (c & 1), yi = y0 + (c >> 1);
            bool ok = (xi >= 0) && (xi < 64) && (yi >= 0) && (yi < 64);
            float wgt = ((c & 1) ? wx : 1.0f - wx) * ((c >> 1) ? wy : 1.0f - wy);
            s_idx[hp][c] = ok ? (yi * 64 + xi) : -1;
            s_w[hp][c] = wgt;
        }
    }
    __syncthreads();
    const int h = t >> 5, dd = t & 31;
    const float* vb = val + (size_t)b * HWTOT * DM + h * 32 + dd;
    float acc = 0.0f;
#pragma unroll
    for (int p = 0; p < 4; ++p) {
        float aw = s_attn[h * 4 + p];
#pragma unroll
        for (int c = 0; c < 4; ++c) {
            int idx = s_idx[h * 4 + p][c];
            if (idx >= 0) acc += aw * s_w[h * 4 + p][c] * vb[(size_t)idx * DM];
        }
    }
    oms[(size_t)bq * DM + t] = acc;
}

// ---------------- fused residual-add + LayerNorm, in-place on q. one wave per row.
__global__ __launch_bounds__(256) void add_ln(
    float* __restrict__ q, const float* __restrict__ r,
    const float* __restrict__ g, const float* __restrict__ bta)
{
    const int row = blockIdx.x * 4 + (threadIdx.x >> 6);
    const int lane = threadIdx.x & 63;
    float4* qp = (float4*)(q + (size_t)row * DM);
    const float4* rp = (const float4*)(r + (size_t)row * DM);
    float4 a = qp[lane];
    float4 c = rp[lane];
    float x0 = a.x + c.x, x1 = a.y + c.y, x2 = a.z + c.z, x3 = a.w + c.w;
    float s = x0 + x1 + x2 + x3;
#pragma unroll
    for (int o = 32; o > 0; o >>= 1) s += __shfl_down(s, o);
    float mean = __shfl(s, 0) * (1.0f / 256.0f);
    float d0 = x0 - mean, d1 = x1 - mean, d2 = x2 - mean, d3 = x3 - mean;
    float vs = d0 * d0 + d1 * d1 + d2 * d2 + d3 * d3;
#pragma unroll
    for (int o = 32; o > 0; o >>= 1) vs += __shfl_down(vs, o);
    float rstd = rsqrtf(__shfl(vs, 0) * (1.0f / 256.0f) + EPSV);
    int base = lane * 4;
    float4 o4;
    o4.x = d0 * rstd * g[base + 0] + bta[base + 0];
    o4.y = d1 * rstd * g[base + 1] + bta[base + 1];
    o4.z = d2 * rstd * g[base + 2] + bta[base + 2];
    o4.w = d3 * rstd * g[base + 3] + bta[base + 3];
    qp[lane] = o4;
}

// ---------------- broadcast query_embed to all batches
__global__ __launch_bounds__(256) void bcast_q(
    const float4* __restrict__ qe, float4* __restrict__ q)
{
    const int i = blockIdx.x * 256 + threadIdx.x;  // HW*D/4 = 262144 total
    float4 v = qe[i];
#pragma unroll
    for (int b = 0; b < BBATCH; ++b) q[(size_t)b * (HWTOT * DM / 4) + i] = v;
}

extern "C" void kernel_launch(void* const* d_in, const int* in_sizes, int n_in,
                              void* d_out, int out_size, void* d_ws, size_t ws_size,
                              hipStream_t stream)
{
    (void)in_sizes; (void)n_in; (void)out_size; (void)ws_size;
    const float* x     = (const float*)d_in[0];
    const float* W_in  = (const float*)d_in[1];
    const float* bn1_g = (const float*)d_in[2];
    const float* bn1_b = (const float*)d_in[3];
    const float* bn1_m = (const float*)d_in[4];
    const float* bn1_v = (const float*)d_in[5];
    const float* qe    = (const float*)d_in[6];
    const float* Woff  = (const float*)d_in[7];
    const float* boff  = (const float*)d_in[8];
    const float* Wattn = (const float*)d_in[9];
    const float* battn = (const float*)d_in[10];
    const float* Wval  = (const float*)d_in[11];
    const float* bval  = (const float*)d_in[12];
    const float* Wo    = (const float*)d_in[13];
    const float* bo    = (const float*)d_in[14];
    const float* ln1_g = (const float*)d_in[15];
    const float* ln1_b = (const float*)d_in[16];
    const float* W1    = (const float*)d_in[17];
    const float* b1    = (const float*)d_in[18];
    const float* W2    = (const float*)d_in[19];
    const float* b2    = (const float*)d_in[20];
    const float* ln2_g = (const float*)d_in[21];
    const float* ln2_b = (const float*)d_in[22];
    const float* W_out = (const float*)d_in[23];
    const float* bn2_g = (const float*)d_in[24];
    const float* bn2_b = (const float*)d_in[25];
    const float* bn2_m = (const float*)d_in[26];
    const float* bn2_v = (const float*)d_in[27];
    float* out = (float*)d_out;

    float* ws = (float*)d_ws;
    const size_t NQ = (size_t)BBATCH * HWTOT;  // 32768
    float* src  = ws;                 // NQ*D
    float* qb   = src + NQ * DM;      // NQ*D
    float* val  = qb + NQ * DM;       // NQ*D  (reused as o_proj)
    float* offb = val + NQ * DM;      // NQ*64
    float* attb = offb + NQ * 64;     // NQ*32
    float* oms  = attb + NQ * 32;     // NQ*D  (reused as ffn_out)
    float* hbuf = oms + NQ * DM;      // 8192*DFF (FFN chunked x4)
    // total ~45.1M floats = ~180 MB of workspace

    bcast_q<<<dim3(HWTOT * DM / 4 / 256), 256, 0, stream>>>((const float4*)qe, (float4*)qb);
    gemm_projin<<<dim3(DM / 64, HWTOT / 64, BBATCH), 256, 0, stream>>>(
        x, W_in, bn1_g, bn1_b, bn1_m, bn1_v, src);

    const int M = (int)NQ;
    for (int i = 0; i < LYR; ++i) {
        gemm_rm<<<dim3(DM / 64, M / 64), 256, 0, stream>>>(
            src, Wval + (size_t)i * DM * DM, bval + i * DM, val, M, DM, DM, 0);
        gemm_rm<<<dim3(1, M / 64), 256, 0, stream>>>(
            qb, Woff + (size_t)i * DM * 64, boff + i * 64, offb, M, 64, DM, 0);
        gemm_rm<<<dim3(1, M / 64), 256, 0, stream>>>(
            qb, Wattn + (size_t)i * DM * 32, battn + i * 32, attb, M, 32, DM, 0);
        sample_kernel<<<dim3(M), 256, 0, stream>>>(val, offb, attb, oms);
        gemm_rm<<<dim3(DM / 64, M / 64), 256, 0, stream>>>(
            oms, Wo + (size_t)i * DM * DM, bo + i * DM, val, M, DM, DM, 0);
        add_ln<<<dim3(M / 4), 256, 0, stream>>>(qb, val, ln1_g + i * DM, ln1_b + i * DM);
        for (int c = 0; c < 4; ++c) {  // FFN in 4 row-chunks to bound hbuf
            float* qc = qb + (size_t)c * 8192 * DM;
            float* fc = oms + (size_t)c * 8192 * DM;
            gemm_rm<<<dim3(DFFN / 64, 8192 / 64), 256, 0, stream>>>(
                qc, W1 + (size_t)i * DM * DFFN, b1 + i * DFFN, hbuf, 8192, DFFN, DM, 1);
            gemm_rm<<<dim3(DM / 64, 8192 / 64), 256, 0, stream>>>(
                hbuf, W2 + (size_t)i * DFFN * DM, b2 + i * DM, fc, 8192, DM, DFFN, 0);
        }
        add_ln<<<dim3(M / 4), 256, 0, stream>>>(qb, oms, ln2_g + i * DM, ln2_b + i * DM);
    }
    gemm_projout<<<dim3(HWTOT / 64, CINC / 64, BBATCH), 256, 0, stream>>>(
        qb, W_out, bn2_g, bn2_b, bn2_m, bn2_v, out);
}

// Round 2
// 880.773 us; speedup vs baseline: 2.7578x; 2.7578x over previous
//
#include <hip/hip_runtime.h>
#include <cstdint>

#define LYR 2
#define DM  256
#define DFFN 1024
#define CINC 512
#define BBATCH 8
#define HWTOT 4096
#define EPSV 1e-5f

using u16 = unsigned short;
typedef __attribute__((ext_vector_type(8))) short bf16x8;
typedef __attribute__((ext_vector_type(4))) float f32x4;

__device__ inline u16 f2b(float v) {
    union { float f; uint32_t u; } x; x.f = v;
    uint32_t r = x.u + 0x7fffu + ((x.u >> 16) & 1u);
    return (u16)(r >> 16);
}
__device__ inline float b2f(u16 u) {
    union { uint32_t i; float f; } x; x.i = ((uint32_t)u) << 16; return x.f;
}

// ================= bf16 MFMA GEMM: C = A(M,K) @ Bt(N,K)^T, 128x128 tile =================
// MODE 0: bf16 out, x+shift[col]          (val)
// MODE 1: bf16 out, relu(x*scale[col]+shift[col])  (proj_in)
// MODE 2: fp32 out, x+shift[col]          (offattn, Wo, FFN2)
// MODE 3: fp32 out, relu(x*scale[row]+shift[row])  (proj_out)
// MODE 4: bf16 out, relu(x+shift[col])    (FFN1)
template<int MODE>
__global__ __launch_bounds__(256) void mfma_gemm(
    const u16* __restrict__ A, const u16* __restrict__ Bt,
    const float* __restrict__ scale, const float* __restrict__ shift,
    void* __restrict__ Cv, int M, int N, int K, int ldc,
    long long a_zs, long long b_zs, long long c_zs)
{
    __shared__ u16 As[4096];
    __shared__ u16 Bs[4096];
    const int tid = threadIdx.x;
    const int lane = tid & 63;
    const int wid = tid >> 6;
    const int wm = (wid & 1) << 6, wn = (wid >> 1) << 6;
    const int quad = lane >> 4, r = lane & 15;
    const int m0 = blockIdx.y << 7, n0 = blockIdx.x << 7;
    const u16* Ab = A + (long long)blockIdx.z * a_zs + (long long)m0 * K;
    const u16* Bb = Bt + (long long)blockIdx.z * b_zs + (long long)n0 * K;

    // staging: unit u (16B) holds row m=u>>2, k-block c=(u&3)^((m>>1)&3) (swizzle)
    const int u0 = tid, u1 = tid + 256;
    const int mu0 = u0 >> 2, cu0 = (u0 & 3) ^ ((mu0 >> 1) & 3);
    const int mu1 = u1 >> 2, cu1 = (u1 & 3) ^ ((mu1 >> 1) & 3);
    const long long ga0 = (long long)mu0 * K + cu0 * 8;
    const long long ga1 = (long long)mu1 * K + cu1 * 8;

    int aoff[4], boff[4];
#pragma unroll
    for (int t = 0; t < 4; ++t) {
        int m = wm + t * 16 + r;
        aoff[t] = (m * 4 + (quad ^ ((m >> 1) & 3))) * 8;
        int n = wn + t * 16 + r;
        boff[t] = (n * 4 + (quad ^ ((n >> 1) & 3))) * 8;
    }

    f32x4 acc[4][4];
#pragma unroll
    for (int i = 0; i < 4; ++i)
#pragma unroll
        for (int j = 0; j < 4; ++j) acc[i][j] = (f32x4){0.f, 0.f, 0.f, 0.f};

    for (int k0 = 0; k0 < K; k0 += 32) {
        __builtin_amdgcn_global_load_lds((const __attribute__((address_space(1))) void*)(Ab + ga0 + k0),
                                         (__attribute__((address_space(3))) void*)(As + u0 * 8), 16, 0, 0);
        __builtin_amdgcn_global_load_lds((const __attribute__((address_space(1))) void*)(Ab + ga1 + k0),
                                         (__attribute__((address_space(3))) void*)(As + u1 * 8), 16, 0, 0);
        __builtin_amdgcn_global_load_lds((const __attribute__((address_space(1))) void*)(Bb + ga0 + k0),
                                         (__attribute__((address_space(3))) void*)(Bs + u0 * 8), 16, 0, 0);
        __builtin_amdgcn_global_load_lds((const __attribute__((address_space(1))) void*)(Bb + ga1 + k0),
                                         (__attribute__((address_space(3))) void*)(Bs + u1 * 8), 16, 0, 0);
        __syncthreads();
        bf16x8 af[4], bf[4];
#pragma unroll
        for (int t = 0; t < 4; ++t) af[t] = *(const bf16x8*)(As + aoff[t]);
#pragma unroll
        for (int t = 0; t < 4; ++t) bf[t] = *(const bf16x8*)(Bs + boff[t]);
#pragma unroll
        for (int i = 0; i < 4; ++i)
#pragma unroll
            for (int j = 0; j < 4; ++j)
                acc[i][j] = __builtin_amdgcn_mfma_f32_16x16x32_bf16(af[i], bf[j], acc[i][j], 0, 0, 0);
        __syncthreads();
    }

    const long long zc = (long long)blockIdx.z * c_zs;
#pragma unroll
    for (int i = 0; i < 4; ++i) {
        const int rowb = m0 + wm + i * 16 + quad * 4;
#pragma unroll
        for (int j = 0; j < 4; ++j) {
            const int col = n0 + wn + j * 16 + r;
            f32x4 v = acc[i][j];
#pragma unroll
            for (int e = 0; e < 4; ++e) {
                const int rw = rowb + e;
                float x = v[e];
                if (MODE == 0) {
                    ((u16*)Cv)[zc + (long long)rw * ldc + col] = f2b(x + shift[col]);
                } else if (MODE == 1) {
                    ((u16*)Cv)[zc + (long long)rw * ldc + col] = f2b(fmaxf(x * scale[col] + shift[col], 0.f));
                } else if (MODE == 2) {
                    ((float*)Cv)[zc + (long long)rw * ldc + col] = x + shift[col];
                } else if (MODE == 3) {
                    ((float*)Cv)[zc + (long long)rw * ldc + col] = fmaxf(x * scale[rw] + shift[rw], 0.f);
                } else {
                    ((u16*)Cv)[zc + (long long)rw * ldc + col] = f2b(fmaxf(x + shift[col], 0.f));
                }
            }
        }
    }
}

// ================= weight prep: transpose+convert to bf16, BN folds, bias concat =========
__device__ __attribute__((noinline)) void tconv(const float* src, u16* dst, int K, int N, int tk, int tn)
{
    __shared__ float t[32][33];
    const int tx = threadIdx.x & 31, ty = threadIdx.x >> 5;
#pragma unroll
    for (int i = 0; i < 4; ++i)
        t[ty + i * 8][tx] = src[(size_t)(tk * 32 + ty + i * 8) * N + tn * 32 + tx];
    __syncthreads();
#pragma unroll
    for (int i = 0; i < 4; ++i)
        dst[(size_t)(tn * 32 + ty + i * 8) * K + tk * 32 + tx] = f2b(t[tx][ty + i * 8]);
}

__device__ __attribute__((noinline)) void tconv_oa(const float* Woff, const float* Wattn, u16* dst, int tk, int tn)
{
    __shared__ float t[32][33];
    const int tx = threadIdx.x & 31, ty = threadIdx.x >> 5;
#pragma unroll
    for (int i = 0; i < 4; ++i) {
        int k = tk * 32 + ty + i * 8, n = tn * 32 + tx;
        float v = (n < 64) ? Woff[k * 64 + n] : ((n < 96) ? Wattn[k * 32 + n - 64] : 0.f);
        t[ty + i * 8][tx] = v;
    }
    __syncthreads();
#pragma unroll
    for (int i = 0; i < 4; ++i)
        dst[(size_t)(tn * 32 + ty + i * 8) * 256 + tk * 32 + tx] = f2b(t[tx][ty + i * 8]);
}

__global__ __launch_bounds__(256) void prep_weights(
    const float* __restrict__ Wval, const float* __restrict__ Wo,
    const float* __restrict__ W1, const float* __restrict__ W2,
    const float* __restrict__ Woff, const float* __restrict__ Wattn,
    const float* __restrict__ boff, const float* __restrict__ battn,
    const float* __restrict__ W_in, const float* __restrict__ W_out,
    const float* __restrict__ bn1g, const float* __restrict__ bn1b,
    const float* __restrict__ bn1m, const float* __restrict__ bn1v,
    const float* __restrict__ bn2g, const float* __restrict__ bn2b,
    const float* __restrict__ bn2m, const float* __restrict__ bn2v,
    u16* __restrict__ wvalT, u16* __restrict__ woT, u16* __restrict__ w1T,
    u16* __restrict__ w2T, u16* __restrict__ woaT,
    u16* __restrict__ winC, u16* __restrict__ woutC,
    float* __restrict__ bn1sc, float* __restrict__ bn1sh,
    float* __restrict__ bn2sc, float* __restrict__ bn2sh, float* __restrict__ boa)
{
    int bid = blockIdx.x;
    if (bid < 1344) {
        int l = bid / 672, r = bid % 672;
        if (r < 64) tconv(Wval + l * 65536, wvalT + l * 65536, 256, 256, r & 7, r >> 3);
        else if (r < 128) { r -= 64;  tconv(Wo + l * 65536, woT + l * 65536, 256, 256, r & 7, r >> 3); }
        else if (r < 384) { r -= 128; tconv(W1 + l * 262144, w1T + l * 262144, 256, 1024, r & 7, r >> 3); }
        else if (r < 640) { r -= 384; tconv(W2 + l * 262144, w2T + l * 262144, 1024, 256, r & 31, r >> 5); }
        else              { r -= 640; tconv_oa(Woff + l * 16384, Wattn + l * 8192, woaT + l * 32768, r & 7, r >> 3); }
    } else {
        int g = bid - 1344;
        int t = threadIdx.x;
        if (g < 32) {
            int base = g * 4096;
#pragma unroll
            for (int k = 0; k < 16; ++k) winC[base + k * 256 + t] = f2b(W_in[base + k * 256 + t]);
        } else if (g < 64) {
            int base = (g - 32) * 4096;
#pragma unroll
            for (int k = 0; k < 16; ++k) woutC[base + k * 256 + t] = f2b(W_out[base + k * 256 + t]);
        } else {
            { float s = bn1g[t] * rsqrtf(bn1v[t] + EPSV); bn1sc[t] = s; bn1sh[t] = bn1b[t] - bn1m[t] * s; }
            for (int c = 0; c < 2; ++c) {
                int i = c * 256 + t;
                float s = bn2g[i] * rsqrtf(bn2v[i] + EPSV);
                bn2sc[i] = s; bn2sh[i] = bn2b[i] - bn2m[i] * s;
            }
            if (t < 128)
                for (int l = 0; l < 2; ++l)
                    boa[l * 128 + t] = (t < 64) ? boff[l * 64 + t]
                                     : ((t < 96) ? battn[l * 32 + t - 64] : 0.f);
        }
    }
}

// ================= x (B,C,HW) -> xT (B,HW,C) bf16 =================
__global__ __launch_bounds__(256) void transpose_x(const float* __restrict__ x, u16* __restrict__ xT)
{
    __shared__ float t[64][65];
    const int b = blockIdx.z, p0 = blockIdx.y << 6, c0 = blockIdx.x << 6;
    const int tx = threadIdx.x & 63, ty = threadIdx.x >> 6;
    const float* xb = x + ((size_t)b * CINC + c0) * HWTOT + p0;
#pragma unroll
    for (int i = 0; i < 16; ++i)
        t[ty + i * 4][tx] = xb[(size_t)(ty + i * 4) * HWTOT + tx];
    __syncthreads();
    u16* xo = xT + ((size_t)b * HWTOT + p0) * CINC + c0;
#pragma unroll
    for (int i = 0; i < 16; ++i)
        xo[(size_t)(ty + i * 4) * CINC + tx] = f2b(t[tx][ty + i * 4]);
}

// ================= deformable sampling (bf16 val, fused offattn buffer) =================
__global__ __launch_bounds__(256) void sample_kernel(
    const u16* __restrict__ val,      // (B*HW, D) bf16
    const float* __restrict__ oa,     // (B*HW, 128): [0..63]=off, [64..95]=attn logits
    u16* __restrict__ oms)            // (B*HW, D) bf16
{
    const int bq = blockIdx.x;
    const int q = bq & (HWTOT - 1);
    const int b = bq >> 12;
    const int t = threadIdx.x;
    __shared__ float s_off[64];
    __shared__ float s_attn[32];
    __shared__ int   s_idx[32][4];
    __shared__ float s_w[32][4];
    if (t < 64) s_off[t] = oa[(size_t)bq * 128 + t];
    else if (t < 96) s_attn[t - 64] = oa[(size_t)bq * 128 + t];
    __syncthreads();
    if (t < 8) {
        float mx = -1e30f;
#pragma unroll
        for (int p = 0; p < 4; ++p) mx = fmaxf(mx, s_attn[t * 4 + p]);
        float e[4], s = 0.0f;
#pragma unroll
        for (int p = 0; p < 4; ++p) { e[p] = __expf(s_attn[t * 4 + p] - mx); s += e[p]; }
        float inv = 1.0f / s;
#pragma unroll
        for (int p = 0; p < 4; ++p) s_attn[t * 4 + p] = e[p] * inv;
    }
    if (t >= 32 && t < 64) {
        int hp = t - 32;
        int ix = q & 63, iy = q >> 6;
        float gx = (ix + 0.5f) + s_off[hp * 2 + 0] - 0.5f;
        float gy = (iy + 0.5f) + s_off[hp * 2 + 1] - 0.5f;
        float x0f = floorf(gx), y0f = floorf(gy);
        float wx = gx - x0f, wy = gy - y0f;
        int x0 = (int)x0f, y0 = (int)y0f;
#pragma unroll
        for (int c = 0; c < 4; ++c) {
            int xi = x0 + (c & 1), yi = y0 + (c >> 1);
            bool ok = (xi >= 0) && (xi < 64) && (yi >= 0) && (yi < 64);
            float wgt = ((c & 1) ? wx : 1.0f - wx) * ((c >> 1) ? wy : 1.0f - wy);
            s_idx[hp][c] = ok ? (yi * 64 + xi) : -1;
            s_w[hp][c] = wgt;
        }
    }
    __syncthreads();
    const int h = t >> 5, dd = t & 31;
    const u16* vb = val + (size_t)b * HWTOT * DM + h * 32 + dd;
    float acc = 0.0f;
#pragma unroll
    for (int p = 0; p < 4; ++p) {
        float aw = s_attn[h * 4 + p];
#pragma unroll
        for (int c = 0; c < 4; ++c) {
            int idx = s_idx[h * 4 + p][c];
            if (idx >= 0) acc += aw * s_w[h * 4 + p][c] * b2f(vb[(size_t)idx * DM]);
        }
    }
    oms[(size_t)bq * DM + t] = f2b(acc);
}

// ================= fused residual + LayerNorm; writes fp32 q and bf16 q16 =================
__global__ __launch_bounds__(256) void add_ln(
    float* __restrict__ q, u16* __restrict__ q16, const float* __restrict__ r,
    const float* __restrict__ g, const float* __restrict__ bta)
{
    const int row = blockIdx.x * 4 + (threadIdx.x >> 6);
    const int lane = threadIdx.x & 63;
    float4* qp = (float4*)(q + (size_t)row * DM);
    const float4* rp = (const float4*)(r + (size_t)row * DM);
    float4 a = qp[lane];
    float4 c = rp[lane];
    float x0 = a.x + c.x, x1 = a.y + c.y, x2 = a.z + c.z, x3 = a.w + c.w;
    float s = x0 + x1 + x2 + x3;
#pragma unroll
    for (int o = 32; o > 0; o >>= 1) s += __shfl_down(s, o);
    float mean = __shfl(s, 0) * (1.0f / 256.0f);
    float d0 = x0 - mean, d1 = x1 - mean, d2 = x2 - mean, d3 = x3 - mean;
    float vs = d0 * d0 + d1 * d1 + d2 * d2 + d3 * d3;
#pragma unroll
    for (int o = 32; o > 0; o >>= 1) vs += __shfl_down(vs, o);
    float rstd = rsqrtf(__shfl(vs, 0) * (1.0f / 256.0f) + EPSV);
    int base = lane * 4;
    float4 o4;
    o4.x = d0 * rstd * g[base + 0] + bta[base + 0];
    o4.y = d1 * rstd * g[base + 1] + bta[base + 1];
    o4.z = d2 * rstd * g[base + 2] + bta[base + 2];
    o4.w = d3 * rstd * g[base + 3] + bta[base + 3];
    qp[lane] = o4;
    union { u16 u[4]; uint2 w; } pk;
    pk.u[0] = f2b(o4.x); pk.u[1] = f2b(o4.y); pk.u[2] = f2b(o4.z); pk.u[3] = f2b(o4.w);
    ((uint2*)(q16 + (size_t)row * DM))[lane] = pk.w;
}

__global__ __launch_bounds__(256) void bcast_q(
    const float4* __restrict__ qe, float4* __restrict__ q, u16* __restrict__ q16)
{
    const int i = blockIdx.x * 256 + threadIdx.x;  // over HW*D/4 = 262144
    float4 v = qe[i];
    union { u16 u[4]; uint2 w; } pk;
    pk.u[0] = f2b(v.x); pk.u[1] = f2b(v.y); pk.u[2] = f2b(v.z); pk.u[3] = f2b(v.w);
#pragma unroll
    for (int b = 0; b < BBATCH; ++b) {
        q[(size_t)b * 262144 + i] = v;
        ((uint2*)q16)[(size_t)b * 262144 + i] = pk.w;
    }
}

extern "C" void kernel_launch(void* const* d_in, const int* in_sizes, int n_in,
                              void* d_out, int out_size, void* d_ws, size_t ws_size,
                              hipStream_t stream)
{
    (void)in_sizes; (void)n_in; (void)out_size; (void)ws_size;
    const float* x     = (const float*)d_in[0];
    const float* W_in  = (const float*)d_in[1];
    const float* bn1_g = (const float*)d_in[2];
    const float* bn1_b = (const float*)d_in[3];
    const float* bn1_m = (const float*)d_in[4];
    const float* bn1_v = (const float*)d_in[5];
    const float* qe    = (const float*)d_in[6];
    const float* Woff  = (const float*)d_in[7];
    const float* boff  = (const float*)d_in[8];
    const float* Wattn = (const float*)d_in[9];
    const float* battn = (const float*)d_in[10];
    const float* Wval  = (const float*)d_in[11];
    const float* bval  = (const float*)d_in[12];
    const float* Wo    = (const float*)d_in[13];
    const float* bo    = (const float*)d_in[14];
    const float* ln1_g = (const float*)d_in[15];
    const float* ln1_b = (const float*)d_in[16];
    const float* W1    = (const float*)d_in[17];
    const float* b1    = (const float*)d_in[18];
    const float* W2    = (const float*)d_in[19];
    const float* b2    = (const float*)d_in[20];
    const float* ln2_g = (const float*)d_in[21];
    const float* ln2_b = (const float*)d_in[22];
    const float* W_out = (const float*)d_in[23];
    const float* bn2_g = (const float*)d_in[24];
    const float* bn2_b = (const float*)d_in[25];
    const float* bn2_m = (const float*)d_in[26];
    const float* bn2_v = (const float*)d_in[27];
    float* out = (float*)d_out;

    char* w = (char*)d_ws;
    float* q      = (float*)w;  w += 33554432;   // 32768*256 f32
    float* resid  = (float*)w;  w += 33554432;
    float* offat  = (float*)w;  w += 16777216;   // 32768*128 f32
    u16*  q16     = (u16*)w;    w += 16777216;
    u16*  src16   = (u16*)w;    w += 16777216;
    u16*  oms16   = (u16*)w;    w += 16777216;
    u16*  scr     = (u16*)w;    w += 33554432;   // xT (32768*512) | val16 + hbuf
    u16*  wvalT   = (u16*)w;    w += 262144;
    u16*  woT     = (u16*)w;    w += 262144;
    u16*  w1T     = (u16*)w;    w += 1048576;
    u16*  w2T     = (u16*)w;    w += 1048576;
    u16*  woaT    = (u16*)w;    w += 131072;
    u16*  winC    = (u16*)w;    w += 262144;
    u16*  woutC   = (u16*)w;    w += 262144;
    float* bn1sc  = (float*)w;  w += 1024;
    float* bn1sh  = (float*)w;  w += 1024;
    float* bn2sc  = (float*)w;  w += 2048;
    float* bn2sh  = (float*)w;  w += 2048;
    float* boa    = (float*)w;  w += 1024;

    u16* xT     = scr;               // 32768*512, dead after proj_in
    u16* val16  = scr;               // 32768*256
    u16* hbuf16 = scr + 8388608;     // 8192*1024 (FFN chunked x4)

    prep_weights<<<dim3(1409), 256, 0, stream>>>(
        Wval, Wo, W1, W2, Woff, Wattn, boff, battn, W_in, W_out,
        bn1_g, bn1_b, bn1_m, bn1_v, bn2_g, bn2_b, bn2_m, bn2_v,
        wvalT, woT, w1T, w2T, woaT, winC, woutC, bn1sc, bn1sh, bn2sc, bn2sh, boa);
    transpose_x<<<dim3(CINC / 64, HWTOT / 64, BBATCH), 256, 0, stream>>>(x, xT);
    bcast_q<<<dim3(1024), 256, 0, stream>>>((const float4*)qe, (float4*)q, q16);

    // proj_in: (32768,512)@(256,512)^T -> bf16 src
    mfma_gemm<1><<<dim3(2, 256, 1), 256, 0, stream>>>(
        xT, winC, bn1sc, bn1sh, src16, 32768, 256, 512, 256, 0, 0, 0);

    for (int l = 0; l < LYR; ++l) {
        mfma_gemm<0><<<dim3(2, 256, 1), 256, 0, stream>>>(
            src16, wvalT + l * 65536, nullptr, bval + l * 256, val16,
            32768, 256, 256, 256, 0, 0, 0);
        mfma_gemm<2><<<dim3(1, 256, 1), 256, 0, stream>>>(
            q16, woaT + l * 32768, nullptr, boa + l * 128, offat,
            32768, 128, 256, 128, 0, 0, 0);
        sample_kernel<<<dim3(32768), 256, 0, stream>>>(val16, offat, oms16);
        mfma_gemm<2><<<dim3(2, 256, 1), 256, 0, stream>>>(
            oms16, woT + l * 65536, nullptr, bo + l * 256, resid,
            32768, 256, 256, 256, 0, 0, 0);
        add_ln<<<dim3(8192), 256, 0, stream>>>(q, q16, resid, ln1_g + l * 256, ln1_b + l * 256);
        for (int c = 0; c < 4; ++c) {
            mfma_gemm<4><<<dim3(8, 64, 1), 256, 0, stream>>>(
                q16 + (size_t)c * 8192 * 256, w1T + l * 262144, nullptr, b1 + l * 1024,
                hbuf16, 8192, 1024, 256, 1024, 0, 0, 0);
            mfma_gemm<2><<<dim3(2, 64, 1), 256, 0, stream>>>(
                hbuf16, w2T + l * 262144, nullptr, b2 + l * 256,
                resid + (size_t)c * 8192 * 256, 8192, 256, 1024, 256, 0, 0, 0);
        }
        add_ln<<<dim3(8192), 256, 0, stream>>>(q, q16, resid, ln2_g + l * 256, ln2_b + l * 256);
    }

    // proj_out: per-batch (512,256)@(4096,256)^T -> fp32 out (B,C,HW)
    mfma_gemm<3><<<dim3(32, 4, BBATCH), 256, 0, stream>>>(
        woutC, q16, bn2sc, bn2sh, out, 512, 4096, 256, 4096,
        0, (long long)HWTOT * DM, (long long)CINC * HWTOT);
}

// Round 3
// 550.255 us; speedup vs baseline: 4.4143x; 1.6007x over previous
//
#include <hip/hip_runtime.h>
#include <cstdint>

#define LYR 2
#define DM  256
#define DFFN 1024
#define CINC 512
#define BBATCH 8
#define HWTOT 4096
#define EPSV 1e-5f

using u16 = unsigned short;
typedef __attribute__((ext_vector_type(8))) short bf16x8;
typedef __attribute__((ext_vector_type(4))) float f32x4;

__device__ inline u16 f2b(float v) {
    union { float f; uint32_t u; } x; x.f = v;
    uint32_t r = x.u + 0x7fffu + ((x.u >> 16) & 1u);
    return (u16)(r >> 16);
}
__device__ inline float b2f(u16 u) {
    union { uint32_t i; float f; } x; x.i = ((uint32_t)u) << 16; return x.f;
}
__device__ inline float blo(uint32_t d) {
    union { uint32_t i; float f; } x; x.i = d << 16; return x.f;
}
__device__ inline float bhi(uint32_t d) {
    union { uint32_t i; float f; } x; x.i = d & 0xffff0000u; return x.f;
}

// ================= bf16 MFMA GEMM: C = A(M,K) @ Bt(N,K)^T, 128x128 tile =================
// MODE 0: bf16 out, x+shift[col]          (val)
// MODE 1: bf16 out, relu(x*scale[col]+shift[col])  (proj_in)
// MODE 2: fp32 out, x+shift[col]          (offattn, Wo, FFN2)
// MODE 3: fp32 out, relu(x*scale[row]+shift[row])  (proj_out)
// MODE 4: bf16 out, relu(x+shift[col])    (FFN1)
template<int MODE>
__global__ __launch_bounds__(256) void mfma_gemm(
    const u16* __restrict__ A, const u16* __restrict__ Bt,
    const float* __restrict__ scale, const float* __restrict__ shift,
    void* __restrict__ Cv, int M, int N, int K, int ldc,
    long long a_zs, long long b_zs, long long c_zs)
{
    __shared__ u16 As[4096];
    __shared__ u16 Bs[4096];
    const int tid = threadIdx.x;
    const int lane = tid & 63;
    const int wid = tid >> 6;
    const int wm = (wid & 1) << 6, wn = (wid >> 1) << 6;
    const int quad = lane >> 4, r = lane & 15;
    const int m0 = blockIdx.y << 7, n0 = blockIdx.x << 7;
    const u16* Ab = A + (long long)blockIdx.z * a_zs + (long long)m0 * K;
    const u16* Bb = Bt + (long long)blockIdx.z * b_zs + (long long)n0 * K;

    const int u0 = tid, u1 = tid + 256;
    const int mu0 = u0 >> 2, cu0 = (u0 & 3) ^ ((mu0 >> 1) & 3);
    const int mu1 = u1 >> 2, cu1 = (u1 & 3) ^ ((mu1 >> 1) & 3);
    const long long ga0 = (long long)mu0 * K + cu0 * 8;
    const long long ga1 = (long long)mu1 * K + cu1 * 8;

    int aoff[4], boff[4];
#pragma unroll
    for (int t = 0; t < 4; ++t) {
        int m = wm + t * 16 + r;
        aoff[t] = (m * 4 + (quad ^ ((m >> 1) & 3))) * 8;
        int n = wn + t * 16 + r;
        boff[t] = (n * 4 + (quad ^ ((n >> 1) & 3))) * 8;
    }

    f32x4 acc[4][4];
#pragma unroll
    for (int i = 0; i < 4; ++i)
#pragma unroll
        for (int j = 0; j < 4; ++j) acc[i][j] = (f32x4){0.f, 0.f, 0.f, 0.f};

    for (int k0 = 0; k0 < K; k0 += 32) {
        __builtin_amdgcn_global_load_lds((const __attribute__((address_space(1))) void*)(Ab + ga0 + k0),
                                         (__attribute__((address_space(3))) void*)(As + u0 * 8), 16, 0, 0);
        __builtin_amdgcn_global_load_lds((const __attribute__((address_space(1))) void*)(Ab + ga1 + k0),
                                         (__attribute__((address_space(3))) void*)(As + u1 * 8), 16, 0, 0);
        __builtin_amdgcn_global_load_lds((const __attribute__((address_space(1))) void*)(Bb + ga0 + k0),
                                         (__attribute__((address_space(3))) void*)(Bs + u0 * 8), 16, 0, 0);
        __builtin_amdgcn_global_load_lds((const __attribute__((address_space(1))) void*)(Bb + ga1 + k0),
                                         (__attribute__((address_space(3))) void*)(Bs + u1 * 8), 16, 0, 0);
        __syncthreads();
        bf16x8 af[4], bf[4];
#pragma unroll
        for (int t = 0; t < 4; ++t) af[t] = *(const bf16x8*)(As + aoff[t]);
#pragma unroll
        for (int t = 0; t < 4; ++t) bf[t] = *(const bf16x8*)(Bs + boff[t]);
#pragma unroll
        for (int i = 0; i < 4; ++i)
#pragma unroll
            for (int j = 0; j < 4; ++j)
                acc[i][j] = __builtin_amdgcn_mfma_f32_16x16x32_bf16(af[i], bf[j], acc[i][j], 0, 0, 0);
        __syncthreads();
    }

    const long long zc = (long long)blockIdx.z * c_zs;
#pragma unroll
    for (int i = 0; i < 4; ++i) {
        const int rowb = m0 + wm + i * 16 + quad * 4;
#pragma unroll
        for (int j = 0; j < 4; ++j) {
            const int col = n0 + wn + j * 16 + r;
            f32x4 v = acc[i][j];
#pragma unroll
            for (int e = 0; e < 4; ++e) {
                const int rw = rowb + e;
                float x = v[e];
                if (MODE == 0) {
                    ((u16*)Cv)[zc + (long long)rw * ldc + col] = f2b(x + shift[col]);
                } else if (MODE == 1) {
                    ((u16*)Cv)[zc + (long long)rw * ldc + col] = f2b(fmaxf(x * scale[col] + shift[col], 0.f));
                } else if (MODE == 2) {
                    ((float*)Cv)[zc + (long long)rw * ldc + col] = x + shift[col];
                } else if (MODE == 3) {
                    ((float*)Cv)[zc + (long long)rw * ldc + col] = fmaxf(x * scale[rw] + shift[rw], 0.f);
                } else {
                    ((u16*)Cv)[zc + (long long)rw * ldc + col] = f2b(fmaxf(x + shift[col], 0.f));
                }
            }
        }
    }
}

// ================= weight prep =================
__device__ __attribute__((noinline)) void tconv(const float* src, u16* dst, int K, int N, int tk, int tn)
{
    __shared__ float t[32][33];
    const int tx = threadIdx.x & 31, ty = threadIdx.x >> 5;
#pragma unroll
    for (int i = 0; i < 4; ++i)
        t[ty + i * 8][tx] = src[(size_t)(tk * 32 + ty + i * 8) * N + tn * 32 + tx];
    __syncthreads();
#pragma unroll
    for (int i = 0; i < 4; ++i)
        dst[(size_t)(tn * 32 + ty + i * 8) * K + tk * 32 + tx] = f2b(t[tx][ty + i * 8]);
}

__device__ __attribute__((noinline)) void tconv_oa(const float* Woff, const float* Wattn, u16* dst, int tk, int tn)
{
    __shared__ float t[32][33];
    const int tx = threadIdx.x & 31, ty = threadIdx.x >> 5;
#pragma unroll
    for (int i = 0; i < 4; ++i) {
        int k = tk * 32 + ty + i * 8, n = tn * 32 + tx;
        float v = (n < 64) ? Woff[k * 64 + n] : ((n < 96) ? Wattn[k * 32 + n - 64] : 0.f);
        t[ty + i * 8][tx] = v;
    }
    __syncthreads();
#pragma unroll
    for (int i = 0; i < 4; ++i)
        dst[(size_t)(tn * 32 + ty + i * 8) * 256 + tk * 32 + tx] = f2b(t[tx][ty + i * 8]);
}

__global__ __launch_bounds__(256) void prep_weights(
    const float* __restrict__ Wval, const float* __restrict__ Wo,
    const float* __restrict__ W1, const float* __restrict__ W2,
    const float* __restrict__ Woff, const float* __restrict__ Wattn,
    const float* __restrict__ boff, const float* __restrict__ battn,
    const float* __restrict__ W_in, const float* __restrict__ W_out,
    const float* __restrict__ bn1g, const float* __restrict__ bn1b,
    const float* __restrict__ bn1m, const float* __restrict__ bn1v,
    const float* __restrict__ bn2g, const float* __restrict__ bn2b,
    const float* __restrict__ bn2m, const float* __restrict__ bn2v,
    u16* __restrict__ wvalT, u16* __restrict__ woT, u16* __restrict__ w1T,
    u16* __restrict__ w2T, u16* __restrict__ woaT,
    u16* __restrict__ winC, u16* __restrict__ woutC,
    float* __restrict__ bn1sc, float* __restrict__ bn1sh,
    float* __restrict__ bn2sc, float* __restrict__ bn2sh, float* __restrict__ boa)
{
    int bid = blockIdx.x;
    if (bid < 1344) {
        int l = bid / 672, r = bid % 672;
        if (r < 64) tconv(Wval + l * 65536, wvalT + l * 65536, 256, 256, r & 7, r >> 3);
        else if (r < 128) { r -= 64;  tconv(Wo + l * 65536, woT + l * 65536, 256, 256, r & 7, r >> 3); }
        else if (r < 384) { r -= 128; tconv(W1 + l * 262144, w1T + l * 262144, 256, 1024, r & 7, r >> 3); }
        else if (r < 640) { r -= 384; tconv(W2 + l * 262144, w2T + l * 262144, 1024, 256, r & 31, r >> 5); }
        else              { r -= 640; tconv_oa(Woff + l * 16384, Wattn + l * 8192, woaT + l * 32768, r & 7, r >> 3); }
    } else {
        int g = bid - 1344;
        int t = threadIdx.x;
        if (g < 32) {
            int base = g * 4096;
#pragma unroll
            for (int k = 0; k < 16; ++k) winC[base + k * 256 + t] = f2b(W_in[base + k * 256 + t]);
        } else if (g < 64) {
            int base = (g - 32) * 4096;
#pragma unroll
            for (int k = 0; k < 16; ++k) woutC[base + k * 256 + t] = f2b(W_out[base + k * 256 + t]);
        } else {
            { float s = bn1g[t] * rsqrtf(bn1v[t] + EPSV); bn1sc[t] = s; bn1sh[t] = bn1b[t] - bn1m[t] * s; }
            for (int c = 0; c < 2; ++c) {
                int i = c * 256 + t;
                float s = bn2g[i] * rsqrtf(bn2v[i] + EPSV);
                bn2sc[i] = s; bn2sh[i] = bn2b[i] - bn2m[i] * s;
            }
            if (t < 128)
                for (int l = 0; l < 2; ++l)
                    boa[l * 128 + t] = (t < 64) ? boff[l * 64 + t]
                                     : ((t < 96) ? battn[l * 32 + t - 64] : 0.f);
        }
    }
}

// ================= x (B,C,HW) -> xT (B,HW,C) bf16 =================
__global__ __launch_bounds__(256) void transpose_x(const float* __restrict__ x, u16* __restrict__ xT)
{
    __shared__ float t[64][65];
    const int b = blockIdx.z, p0 = blockIdx.y << 6, c0 = blockIdx.x << 6;
    const int tx = threadIdx.x & 63, ty = threadIdx.x >> 6;
    const float* xb = x + ((size_t)b * CINC + c0) * HWTOT + p0;
#pragma unroll
    for (int i = 0; i < 16; ++i)
        t[ty + i * 4][tx] = xb[(size_t)(ty + i * 4) * HWTOT + tx];
    __syncthreads();
    u16* xo = xT + ((size_t)b * HWTOT + p0) * CINC + c0;
#pragma unroll
    for (int i = 0; i < 16; ++i)
        xo[(size_t)(ty + i * 4) * CINC + tx] = f2b(t[tx][ty + i * 4]);
}

// ================= deformable sampling: 8 queries/block, 32 lanes/query =================
struct IW { int eo; float w; };

__global__ __launch_bounds__(256) void sample_kernel(
    const u16* __restrict__ val,      // (B*HW, D) bf16
    const float* __restrict__ oa,     // (B*HW, 128): [0..63]=off, [64..95]=attn logits
    u16* __restrict__ oms)            // (B*HW, D) bf16
{
    __shared__ float s_oa[8][96];
    __shared__ IW s_iw[8][32][5];     // [qi][hp][corner], padded 4->5 to spread banks
    const int t = threadIdx.x;
    const int bq0 = blockIdx.x << 3;
    const int b = blockIdx.x >> 9;

    {   // stage offsets+logits: 24 float4 per query
        int qi = t >> 5, j = t & 31;
        if (j < 24)
            ((float4*)s_oa[qi])[j] = ((const float4*)oa)[((size_t)(bq0 + qi)) * 32 + j];
    }
    __syncthreads();

    {   // per-(query, head, point): softmax weight + 4 corners
        const int qi = t >> 5, hp = t & 31, h = hp >> 2, p = hp & 3;
        const float* so = s_oa[qi];
        float l0 = so[64 + h * 4 + 0], l1 = so[64 + h * 4 + 1];
        float l2 = so[64 + h * 4 + 2], l3 = so[64 + h * 4 + 3];
        float mx = fmaxf(fmaxf(l0, l1), fmaxf(l2, l3));
        float e0 = __expf(l0 - mx), e1 = __expf(l1 - mx), e2 = __expf(l2 - mx), e3 = __expf(l3 - mx);
        float inv = 1.0f / (e0 + e1 + e2 + e3);
        float aw = ((p == 0) ? e0 : (p == 1) ? e1 : (p == 2) ? e2 : e3) * inv;
        const int bq = bq0 + qi;
        float gx = (float)(bq & 63) + so[hp * 2 + 0];
        float gy = (float)((bq >> 6) & 63) + so[hp * 2 + 1];
        float x0f = floorf(gx), y0f = floorf(gy);
        float wx = gx - x0f, wy = gy - y0f;
        int x0 = (int)x0f, y0 = (int)y0f;
#pragma unroll
        for (int c = 0; c < 4; ++c) {
            int xi = x0 + (c & 1), yi = y0 + (c >> 1);
            bool ok = (xi >= 0) && (xi < 64) && (yi >= 0) && (yi < 64);
            float wgt = ((c & 1) ? wx : 1.0f - wx) * ((c >> 1) ? wy : 1.0f - wy);
            s_iw[qi][hp][c].eo = ok ? ((yi * 64 + xi) << 8) : 0;
            s_iw[qi][hp][c].w = ok ? aw * wgt : 0.f;
        }
    }
    __syncthreads();

    {   // gather: lane owns 8 channels of one head for one query
        const int qi = t >> 5, l = t & 31, h = l >> 2, cc = l & 3;
        const u16* base = val + ((size_t)b << 20) + (h << 5) + (cc << 3);
        float a[8] = {0.f, 0.f, 0.f, 0.f, 0.f, 0.f, 0.f, 0.f};
#pragma unroll
        for (int p = 0; p < 4; ++p)
#pragma unroll
            for (int c = 0; c < 4; ++c) {
                IW iw = s_iw[qi][(h << 2) + p][c];
                uint4 v = *(const uint4*)(base + iw.eo);
                a[0] += iw.w * blo(v.x); a[1] += iw.w * bhi(v.x);
                a[2] += iw.w * blo(v.y); a[3] += iw.w * bhi(v.y);
                a[4] += iw.w * blo(v.z); a[5] += iw.w * bhi(v.z);
                a[6] += iw.w * blo(v.w); a[7] += iw.w * bhi(v.w);
            }
        uint4 o;
        o.x = (uint32_t)f2b(a[0]) | ((uint32_t)f2b(a[1]) << 16);
        o.y = (uint32_t)f2b(a[2]) | ((uint32_t)f2b(a[3]) << 16);
        o.z = (uint32_t)f2b(a[4]) | ((uint32_t)f2b(a[5]) << 16);
        o.w = (uint32_t)f2b(a[6]) | ((uint32_t)f2b(a[7]) << 16);
        *(uint4*)(oms + (size_t)(bq0 + qi) * 256 + (h << 5) + (cc << 3)) = o;
    }
}

// ================= fused residual + LayerNorm; writes fp32 q and bf16 q16 =================
__global__ __launch_bounds__(256) void add_ln(
    float* __restrict__ q, u16* __restrict__ q16, const float* __restrict__ r,
    const float* __restrict__ g, const float* __restrict__ bta)
{
    const int row = blockIdx.x * 4 + (threadIdx.x >> 6);
    const int lane = threadIdx.x & 63;
    float4* qp = (float4*)(q + (size_t)row * DM);
    const float4* rp = (const float4*)(r + (size_t)row * DM);
    float4 a = qp[lane];
    float4 c = rp[lane];
    float x0 = a.x + c.x, x1 = a.y + c.y, x2 = a.z + c.z, x3 = a.w + c.w;
    float s = x0 + x1 + x2 + x3;
#pragma unroll
    for (int o = 32; o > 0; o >>= 1) s += __shfl_down(s, o);
    float mean = __shfl(s, 0) * (1.0f / 256.0f);
    float d0 = x0 - mean, d1 = x1 - mean, d2 = x2 - mean, d3 = x3 - mean;
    float vs = d0 * d0 + d1 * d1 + d2 * d2 + d3 * d3;
#pragma unroll
    for (int o = 32; o > 0; o >>= 1) vs += __shfl_down(vs, o);
    float rstd = rsqrtf(__shfl(vs, 0) * (1.0f / 256.0f) + EPSV);
    int base = lane * 4;
    float4 o4;
    o4.x = d0 * rstd * g[base + 0] + bta[base + 0];
    o4.y = d1 * rstd * g[base + 1] + bta[base + 1];
    o4.z = d2 * rstd * g[base + 2] + bta[base + 2];
    o4.w = d3 * rstd * g[base + 3] + bta[base + 3];
    qp[lane] = o4;
    union { u16 u[4]; uint2 w; } pk;
    pk.u[0] = f2b(o4.x); pk.u[1] = f2b(o4.y); pk.u[2] = f2b(o4.z); pk.u[3] = f2b(o4.w);
    ((uint2*)(q16 + (size_t)row * DM))[lane] = pk.w;
}

__global__ __launch_bounds__(256) void bcast_q(
    const float4* __restrict__ qe, float4* __restrict__ q, u16* __restrict__ q16)
{
    const int i = blockIdx.x * 256 + threadIdx.x;
    float4 v = qe[i];
    union { u16 u[4]; uint2 w; } pk;
    pk.u[0] = f2b(v.x); pk.u[1] = f2b(v.y); pk.u[2] = f2b(v.z); pk.u[3] = f2b(v.w);
#pragma unroll
    for (int b = 0; b < BBATCH; ++b) {
        q[(size_t)b * 262144 + i] = v;
        ((uint2*)q16)[(size_t)b * 262144 + i] = pk.w;
    }
}

extern "C" void kernel_launch(void* const* d_in, const int* in_sizes, int n_in,
                              void* d_out, int out_size, void* d_ws, size_t ws_size,
                              hipStream_t stream)
{
    (void)in_sizes; (void)n_in; (void)out_size; (void)ws_size;
    const float* x     = (const float*)d_in[0];
    const float* W_in  = (const float*)d_in[1];
    const float* bn1_g = (const float*)d_in[2];
    const float* bn1_b = (const float*)d_in[3];
    const float* bn1_m = (const float*)d_in[4];
    const float* bn1_v = (const float*)d_in[5];
    const float* qe    = (const float*)d_in[6];
    const float* Woff  = (const float*)d_in[7];
    const float* boff  = (const float*)d_in[8];
    const float* Wattn = (const float*)d_in[9];
    const float* battn = (const float*)d_in[10];
    const float* Wval  = (const float*)d_in[11];
    const float* bval  = (const float*)d_in[12];
    const float* Wo    = (const float*)d_in[13];
    const float* bo    = (const float*)d_in[14];
    const float* ln1_g = (const float*)d_in[15];
    const float* ln1_b = (const float*)d_in[16];
    const float* W1    = (const float*)d_in[17];
    const float* b1    = (const float*)d_in[18];
    const float* W2    = (const float*)d_in[19];
    const float* b2    = (const float*)d_in[20];
    const float* ln2_g = (const float*)d_in[21];
    const float* ln2_b = (const float*)d_in[22];
    const float* W_out = (const float*)d_in[23];
    const float* bn2_g = (const float*)d_in[24];
    const float* bn2_b = (const float*)d_in[25];
    const float* bn2_m = (const float*)d_in[26];
    const float* bn2_v = (const float*)d_in[27];
    float* out = (float*)d_out;

    char* w = (char*)d_ws;
    // pool holds (time-disjoint): xT (33.5MB) | val16+offat+oms16 (50.3MB) | hbuf (67.1MB)
    char* pool    = w;          w += 67108864;
    float* q      = (float*)w;  w += 33554432;   // 32768*256 f32
    float* resid  = (float*)w;  w += 33554432;
    u16*  q16     = (u16*)w;    w += 16777216;
    u16*  src16   = (u16*)w;    w += 16777216;
    u16*  wvalT   = (u16*)w;    w += 262144;
    u16*  woT     = (u16*)w;    w += 262144;
    u16*  w1T     = (u16*)w;    w += 1048576;
    u16*  w2T     = (u16*)w;    w += 1048576;
    u16*  woaT    = (u16*)w;    w += 131072;
    u16*  winC    = (u16*)w;    w += 262144;
    u16*  woutC   = (u16*)w;    w += 262144;
    float* bn1sc  = (float*)w;  w += 1024;
    float* bn1sh  = (float*)w;  w += 1024;
    float* bn2sc  = (float*)w;  w += 2048;
    float* bn2sh  = (float*)w;  w += 2048;
    float* boa    = (float*)w;  w += 1024;

    u16*  xT    = (u16*)pool;                   // 32768*512 bf16, dead after proj_in
    u16*  val16 = (u16*)pool;                   // 32768*256 bf16
    float* offat = (float*)(pool + 16777216);   // 32768*128 f32
    u16*  oms16 = (u16*)(pool + 33554432);      // 32768*256 bf16
    u16*  hbuf16 = (u16*)pool;                  // 32768*1024 bf16 (FFN mid)

    prep_weights<<<dim3(1409), 256, 0, stream>>>(
        Wval, Wo, W1, W2, Woff, Wattn, boff, battn, W_in, W_out,
        bn1_g, bn1_b, bn1_m, bn1_v, bn2_g, bn2_b, bn2_m, bn2_v,
        wvalT, woT, w1T, w2T, woaT, winC, woutC, bn1sc, bn1sh, bn2sc, bn2sh, boa);
    transpose_x<<<dim3(CINC / 64, HWTOT / 64, BBATCH), 256, 0, stream>>>(x, xT);
    bcast_q<<<dim3(1024), 256, 0, stream>>>((const float4*)qe, (float4*)q, q16);

    // proj_in: (32768,512)@(256,512)^T -> bf16 src
    mfma_gemm<1><<<dim3(2, 256, 1), 256, 0, stream>>>(
        xT, winC, bn1sc, bn1sh, src16, 32768, 256, 512, 256, 0, 0, 0);

    for (int l = 0; l < LYR; ++l) {
        mfma_gemm<0><<<dim3(2, 256, 1), 256, 0, stream>>>(
            src16, wvalT + l * 65536, nullptr, bval + l * 256, val16,
            32768, 256, 256, 256, 0, 0, 0);
        mfma_gemm<2><<<dim3(1, 256, 1), 256, 0, stream>>>(
            q16, woaT + l * 32768, nullptr, boa + l * 128, offat,
            32768, 128, 256, 128, 0, 0, 0);
        sample_kernel<<<dim3(4096), 256, 0, stream>>>(val16, offat, oms16);
        mfma_gemm<2><<<dim3(2, 256, 1), 256, 0, stream>>>(
            oms16, woT + l * 65536, nullptr, bo + l * 256, resid,
            32768, 256, 256, 256, 0, 0, 0);
        add_ln<<<dim3(8192), 256, 0, stream>>>(q, q16, resid, ln1_g + l * 256, ln1_b + l * 256);
        mfma_gemm<4><<<dim3(8, 256, 1), 256, 0, stream>>>(
            q16, w1T + l * 262144, nullptr, b1 + l * 1024, hbuf16, 32768, 1024, 256, 1024, 0, 0, 0);
        mfma_gemm<2><<<dim3(2, 256, 1), 256, 0, stream>>>(
            hbuf16, w2T + l * 262144, nullptr, b2 + l * 256, resid, 32768, 256, 1024, 256, 0, 0, 0);
        add_ln<<<dim3(8192), 256, 0, stream>>>(q, q16, resid, ln2_g + l * 256, ln2_b + l * 256);
    }

    // proj_out: per-batch (512,256)@(4096,256)^T -> fp32 out (B,C,HW)
    mfma_gemm<3><<<dim3(32, 4, BBATCH), 256, 0, stream>>>(
        woutC, q16, bn2sc, bn2sh, out, 512, 4096, 256, 4096,
        0, (long long)HWTOT * DM, (long long)CINC * HWTOT);
}